// Round 1
// baseline (4796.995 us; speedup 1.0000x reference)
//
#include <hip/hip_runtime.h>
#include <math.h>

#define NTOK 577
#define NB 8
#define NC 1024
#define NH 16
#define HD 64
#define M_ROWS (NB*NTOK)               // 4616
#define SZ ((size_t)NB*NH*NTOK*HD)     // 4726784 floats = B*N*C

// ---------------------------------------------------------------------------
// GEMM 1: qkv = x @ qkv_w^T + qkv_b, scattered into q,k,v [B,H,N,HD]
// x is [N,B,C]; qkv_w is [3C,C] (NT gemm: both K-contiguous)
// ---------------------------------------------------------------------------
__global__ __launch_bounds__(256) void gemm_qkv(const float* __restrict__ X,
        const float* __restrict__ W, const float* __restrict__ bias,
        float* __restrict__ q, float* __restrict__ k, float* __restrict__ v)
{
    __shared__ float as[64][17];
    __shared__ float bs[64][17];
    int tid = threadIdx.x;
    int tx = tid & 15, ty = tid >> 4;
    int row0 = blockIdx.x * 64, col0 = blockIdx.y * 64;

    int lr = tid >> 2;            // 0..63 tile row to load
    int lk = (tid & 3) * 4;       // k offset 0,4,8,12
    int am = row0 + lr;
    bool aval = am < M_ROWS;
    int ab = aval ? am / NTOK : 0, an = aval ? am % NTOK : 0;
    const float* asrc = X + ((size_t)an * NB + ab) * NC;
    const float* bsrc = W + (size_t)(col0 + lr) * NC;

    float acc[4][4];
    #pragma unroll
    for (int i = 0; i < 4; i++)
        #pragma unroll
        for (int j = 0; j < 4; j++) acc[i][j] = 0.f;

    for (int k0 = 0; k0 < NC; k0 += 16) {
        if (aval) {
            float4 t = *(const float4*)(asrc + k0 + lk);
            as[lr][lk+0]=t.x; as[lr][lk+1]=t.y; as[lr][lk+2]=t.z; as[lr][lk+3]=t.w;
        } else {
            as[lr][lk+0]=0.f; as[lr][lk+1]=0.f; as[lr][lk+2]=0.f; as[lr][lk+3]=0.f;
        }
        {
            float4 t = *(const float4*)(bsrc + k0 + lk);
            bs[lr][lk+0]=t.x; bs[lr][lk+1]=t.y; bs[lr][lk+2]=t.z; bs[lr][lk+3]=t.w;
        }
        __syncthreads();
        #pragma unroll
        for (int kk = 0; kk < 16; kk++) {
            float af[4], bf[4];
            #pragma unroll
            for (int i = 0; i < 4; i++) af[i] = as[ty*4+i][kk];
            #pragma unroll
            for (int j = 0; j < 4; j++) bf[j] = bs[tx*4+j][kk];
            #pragma unroll
            for (int i = 0; i < 4; i++)
                #pragma unroll
                for (int j = 0; j < 4; j++) acc[i][j] += af[i]*bf[j];
        }
        __syncthreads();
    }
    #pragma unroll
    for (int i = 0; i < 4; i++) {
        int m = row0 + ty*4 + i;
        if (m >= M_ROWS) continue;
        int b_ = m / NTOK, n_ = m % NTOK;
        #pragma unroll
        for (int j = 0; j < 4; j++) {
            int col = col0 + tx*4 + j;
            float val = acc[i][j] + bias[col];
            int t = col >> 10, h = (col >> 6) & 15, d = col & 63;
            float* dst = (t == 0) ? q : (t == 1 ? k : v);
            dst[(((size_t)b_*NH + h)*NTOK + n_)*HD + d] = val;
        }
    }
}

// ---------------------------------------------------------------------------
// GEMM 2: out[n,b,:] = alpha*(heads[b,:,n,:] flattened @ proj_w^T) + proj_b
// heads is [B,H,N,HD]
// ---------------------------------------------------------------------------
__global__ __launch_bounds__(256) void gemm_proj(const float* __restrict__ Hd,
        const float* __restrict__ W, const float* __restrict__ bias,
        float* __restrict__ out, float alpha)
{
    __shared__ float as[64][17];
    __shared__ float bs[64][17];
    int tid = threadIdx.x;
    int tx = tid & 15, ty = tid >> 4;
    int row0 = blockIdx.x * 64, col0 = blockIdx.y * 64;

    int lr = tid >> 2;
    int lk = (tid & 3) * 4;
    int am = row0 + lr;
    bool aval = am < M_ROWS;
    int ab = aval ? am / NTOK : 0, an = aval ? am % NTOK : 0;
    const float* bsrc = W + (size_t)(col0 + lr) * NC;

    float acc[4][4];
    #pragma unroll
    for (int i = 0; i < 4; i++)
        #pragma unroll
        for (int j = 0; j < 4; j++) acc[i][j] = 0.f;

    for (int k0 = 0; k0 < NC; k0 += 16) {
        int c = k0 + lk;
        int h = c >> 6, d = c & 63;
        if (aval) {
            float4 t = *(const float4*)(Hd + (((size_t)ab*NH + h)*NTOK + an)*HD + d);
            as[lr][lk+0]=t.x; as[lr][lk+1]=t.y; as[lr][lk+2]=t.z; as[lr][lk+3]=t.w;
        } else {
            as[lr][lk+0]=0.f; as[lr][lk+1]=0.f; as[lr][lk+2]=0.f; as[lr][lk+3]=0.f;
        }
        {
            float4 t = *(const float4*)(bsrc + k0 + lk);
            bs[lr][lk+0]=t.x; bs[lr][lk+1]=t.y; bs[lr][lk+2]=t.z; bs[lr][lk+3]=t.w;
        }
        __syncthreads();
        #pragma unroll
        for (int kk = 0; kk < 16; kk++) {
            float af[4], bf[4];
            #pragma unroll
            for (int i = 0; i < 4; i++) af[i] = as[ty*4+i][kk];
            #pragma unroll
            for (int j = 0; j < 4; j++) bf[j] = bs[tx*4+j][kk];
            #pragma unroll
            for (int i = 0; i < 4; i++)
                #pragma unroll
                for (int j = 0; j < 4; j++) acc[i][j] += af[i]*bf[j];
        }
        __syncthreads();
    }
    #pragma unroll
    for (int i = 0; i < 4; i++) {
        int m = row0 + ty*4 + i;
        if (m >= M_ROWS) continue;
        int b_ = m / NTOK, n_ = m % NTOK;
        #pragma unroll
        for (int j = 0; j < 4; j++) {
            int col = col0 + tx*4 + j;
            out[((size_t)n_*NB + b_)*NC + col] = alpha * acc[i][j] + bias[col];
        }
    }
}

// ---------------------------------------------------------------------------
// Flash attention, fp32. O = softmax(Q K^T * scale) V, per (b,h).
// scale = itemp[b] if itemp != null, else cscale. accumulate: O += result.
// Q,K,V,O are [B,H,N,HD]. 32-row Q tile per block, 256 threads.
// ---------------------------------------------------------------------------
__global__ __launch_bounds__(256) void flash_attn(const float* __restrict__ Q,
        const float* __restrict__ K, const float* __restrict__ V,
        float* __restrict__ O, const float* __restrict__ itemp,
        float cscale, int accumulate)
{
    __shared__ float qs[32][65];
    __shared__ float ks[32][65];
    __shared__ float vs[32][65];
    __shared__ float ps[32][33];

    int tid = threadIdx.x;
    int bh = blockIdx.y;                 // 0..127
    int b = bh >> 4;
    int qt = blockIdx.x;                 // 0..18
    float scale = itemp ? itemp[b] : cscale;
    const size_t base = (size_t)bh * NTOK * HD;

    int r = tid >> 3;                    // 0..31 : score/output row
    int sub = tid & 7;
    int qrow = qt*32 + r;
    int d0 = sub * 8;

    // load Q tile (zeros for invalid rows)
    if (qrow < NTOK) {
        const float* src = Q + base + (size_t)qrow*HD + d0;
        float4 t0 = *(const float4*)src;
        float4 t1 = *(const float4*)(src + 4);
        qs[r][d0+0]=t0.x; qs[r][d0+1]=t0.y; qs[r][d0+2]=t0.z; qs[r][d0+3]=t0.w;
        qs[r][d0+4]=t1.x; qs[r][d0+5]=t1.y; qs[r][d0+6]=t1.z; qs[r][d0+7]=t1.w;
    } else {
        #pragma unroll
        for (int i = 0; i < 8; i++) qs[r][d0+i] = 0.f;
    }

    float acc[8];
    #pragma unroll
    for (int j = 0; j < 8; j++) acc[j] = 0.f;
    float mrun = -1e30f, lrun = 0.f;
    int mbase = sub * 4;

    for (int kt = 0; kt < 19; kt++) {
        int grow = kt*32 + r;
        if (grow < NTOK) {
            const float* ksrc = K + base + (size_t)grow*HD + d0;
            const float* vsrc = V + base + (size_t)grow*HD + d0;
            float4 t0 = *(const float4*)ksrc;
            float4 t1 = *(const float4*)(ksrc + 4);
            ks[r][d0+0]=t0.x; ks[r][d0+1]=t0.y; ks[r][d0+2]=t0.z; ks[r][d0+3]=t0.w;
            ks[r][d0+4]=t1.x; ks[r][d0+5]=t1.y; ks[r][d0+6]=t1.z; ks[r][d0+7]=t1.w;
            t0 = *(const float4*)vsrc;
            t1 = *(const float4*)(vsrc + 4);
            vs[r][d0+0]=t0.x; vs[r][d0+1]=t0.y; vs[r][d0+2]=t0.z; vs[r][d0+3]=t0.w;
            vs[r][d0+4]=t1.x; vs[r][d0+5]=t1.y; vs[r][d0+6]=t1.z; vs[r][d0+7]=t1.w;
        } else {
            #pragma unroll
            for (int i = 0; i < 8; i++) { ks[r][d0+i] = 0.f; vs[r][d0+i] = 0.f; }
        }
        __syncthreads();

        // scores: this thread owns rows r, keys mbase..mbase+3
        float s[4] = {0.f, 0.f, 0.f, 0.f};
        for (int d = 0; d < 64; d++) {
            float qv = qs[r][d];
            #pragma unroll
            for (int mm = 0; mm < 4; mm++) s[mm] += qv * ks[mbase+mm][d];
        }
        float tm = -1e30f;
        #pragma unroll
        for (int mm = 0; mm < 4; mm++) {
            if (kt*32 + mbase + mm >= NTOK) s[mm] = -1e30f;
            else s[mm] *= scale;
            tm = fmaxf(tm, s[mm]);
        }
        tm = fmaxf(tm, __shfl_xor(tm, 1));
        tm = fmaxf(tm, __shfl_xor(tm, 2));
        tm = fmaxf(tm, __shfl_xor(tm, 4));
        float mnew = fmaxf(mrun, tm);
        float corr = __expf(mrun - mnew);
        float p[4], psum = 0.f;
        #pragma unroll
        for (int mm = 0; mm < 4; mm++) { p[mm] = __expf(s[mm] - mnew); psum += p[mm]; }
        psum += __shfl_xor(psum, 1);
        psum += __shfl_xor(psum, 2);
        psum += __shfl_xor(psum, 4);
        lrun = lrun * corr + psum;
        mrun = mnew;
        #pragma unroll
        for (int j = 0; j < 8; j++) acc[j] *= corr;
        #pragma unroll
        for (int mm = 0; mm < 4; mm++) ps[r][mbase+mm] = p[mm];
        __syncthreads();

        // PV: acc[j] += sum_m P[r][m] * V[m][d0+j]
        for (int m2 = 0; m2 < 32; m2++) {
            float pv = ps[r][m2];
            #pragma unroll
            for (int j = 0; j < 8; j++) acc[j] += pv * vs[m2][d0+j];
        }
        __syncthreads();
    }

    if (qrow < NTOK) {
        float inv = 1.f / lrun;
        float* dst = O + base + (size_t)qrow*HD + d0;
        #pragma unroll
        for (int j = 0; j < 8; j++) {
            float o = acc[j] * inv;
            if (accumulate) o += dst[j];
            dst[j] = o;
        }
    }
}

// ---------------------------------------------------------------------------
// per-(b,n) L2 norm of x rows → rn[b*N+n]
// ---------------------------------------------------------------------------
__global__ __launch_bounds__(256) void row_norm(const float* __restrict__ X,
                                                float* __restrict__ rn)
{
    int id = blockIdx.x;                 // b*NTOK + n
    int b = id / NTOK, n = id % NTOK;
    const float* src = X + ((size_t)n*NB + b)*NC;
    int tid = threadIdx.x;
    float s = 0.f;
    for (int i = tid; i < NC; i += 256) { float t = src[i]; s += t*t; }
    #pragma unroll
    for (int o = 1; o < 64; o <<= 1) s += __shfl_xor(s, o);
    __shared__ float red[4];
    if ((tid & 63) == 0) red[tid >> 6] = s;
    __syncthreads();
    if (tid == 0) rn[id] = sqrtf(red[0] + red[1] + red[2] + red[3]);
}

__global__ __launch_bounds__(256) void calc_invtemp(const float* __restrict__ rn,
                                                    float* __restrict__ it)
{
    int b = blockIdx.x;
    int tid = threadIdx.x;
    float s = 0.f;
    for (int i = tid; i < NTOK; i += 256) s += rn[b*NTOK + i];
    #pragma unroll
    for (int o = 1; o < 64; o <<= 1) s += __shfl_xor(s, o);
    __shared__ float red[4];
    if ((tid & 63) == 0) red[tid >> 6] = s;
    __syncthreads();
    if (tid == 0) it[b] = (red[0]+red[1]+red[2]+red[3]) / (float)NTOK * 0.125f;
}

// ---------------------------------------------------------------------------
// row-wise L2 normalize, rows of 64 (4 rows per block, one wave each)
// ---------------------------------------------------------------------------
__global__ __launch_bounds__(256) void l2n_rows(const float* __restrict__ in,
                                                float* __restrict__ out)
{
    size_t row = (size_t)blockIdx.x * 4 + (threadIdx.x >> 6);
    int lane = threadIdx.x & 63;
    float x = in[row*HD + lane];
    float s = x*x;
    #pragma unroll
    for (int o = 1; o < 64; o <<= 1) s += __shfl_xor(s, o);
    float nrm = fmaxf(sqrtf(s), 1e-12f);
    out[row*HD + lane] = x / nrm;
}

// ---------------------------------------------------------------------------
extern "C" void kernel_launch(void* const* d_in, const int* in_sizes, int n_in,
                              void* d_out, int out_size, void* d_ws, size_t ws_size,
                              hipStream_t stream)
{
    const float* x      = (const float*)d_in[0];
    const float* qkv_w  = (const float*)d_in[1];
    const float* qkv_b  = (const float*)d_in[2];
    const float* proj_w = (const float*)d_in[3];
    const float* proj_b = (const float*)d_in[4];
    float* out = (float*)d_out;            // [0,SZ)=x_gem, [SZ,2SZ)=x_ori
    float* ws  = (float*)d_ws;

    float* q  = ws;
    float* k  = ws + SZ;
    float* v  = ws + 2*SZ;
    float* b4 = ws + 3*SZ;
    float* rn = ws + 4*SZ;
    float* it = rn + M_ROWS;
    float* b5 = out;                       // x_gem half doubles as scratch

    dim3 blk(256);
    dim3 gqkv(73, 48), gproj(73, 16), gfl(19, 128);

    // q,k,v
    gemm_qkv<<<gqkv, blk, 0, stream>>>(x, qkv_w, qkv_b, q, k, v);
    // inv_temp
    row_norm<<<dim3(M_ROWS), blk, 0, stream>>>(x, rn);
    calc_invtemp<<<dim3(NB), blk, 0, stream>>>(rn, it);
    // x_ori = proj(softmax(qk/8)v)
    flash_attn<<<gfl, blk, 0, stream>>>(q, k, v, b4, nullptr, 0.125f, 0);
    gemm_proj<<<gproj, blk, 0, stream>>>(b4, proj_w, proj_b, out + SZ, 1.f);
    // xs_i = l2n(v,k,q);   k,q normalized in place (dead otherwise)
    l2n_rows<<<dim3(18464), blk, 0, stream>>>(v, b4);   // xs1
    l2n_rows<<<dim3(18464), blk, 0, stream>>>(k, k);    // xs2
    l2n_rows<<<dim3(18464), blk, 0, stream>>>(q, q);    // xs3
    // one self-attn iteration: ys_i = softmax(xs_i xs_i^T * it) xs_i
    flash_attn<<<gfl, blk, 0, stream>>>(b4, b4, b4, b5, it, 0.f, 0);  // ys1 -> out scratch
    flash_attn<<<gfl, blk, 0, stream>>>(k,  k,  k,  b4, it, 0.f, 0);  // ys2 -> b4
    flash_attn<<<gfl, blk, 0, stream>>>(q,  q,  q,  k,  it, 0.f, 0);  // ys3 -> k
    // z_i = l2n(ys_i), in place
    l2n_rows<<<dim3(18464), blk, 0, stream>>>(b5, b5);
    l2n_rows<<<dim3(18464), blk, 0, stream>>>(b4, b4);
    l2n_rows<<<dim3(18464), blk, 0, stream>>>(k,  k);
    // sum_i softmax(z_i z_i^T * it) @ v  -> q
    flash_attn<<<gfl, blk, 0, stream>>>(b5, b5, v, q, it, 0.f, 0);
    flash_attn<<<gfl, blk, 0, stream>>>(b4, b4, v, q, it, 0.f, 1);
    flash_attn<<<gfl, blk, 0, stream>>>(k,  k,  v, q, it, 0.f, 1);
    // x_gem = proj(sum/3)
    gemm_proj<<<gproj, blk, 0, stream>>>(q, proj_w, proj_b, out, 1.f/3.f);
}

// Round 5
// 1666.389 us; speedup vs baseline: 2.8787x; 2.8787x over previous
//
#include <hip/hip_runtime.h>
#include <math.h>

#define NTOK 577
#define NB 8
#define NC 1024
#define NH 16
#define HD 64
#define M_ROWS (NB*NTOK)               // 4616
#define SZ ((size_t)NB*NH*NTOK*HD)     // 4726784 floats = B*N*C

typedef __attribute__((ext_vector_type(8)))  short bf16x8_t;
typedef __attribute__((ext_vector_type(16))) float f32x16_t;

union U4 { unsigned short s[8]; unsigned int u[4]; bf16x8_t v; };

__device__ inline unsigned short f2bf(float x){
    unsigned int u = __float_as_uint(x);
    u = (u + 0x7FFFu + ((u>>16)&1u)) >> 16;
    return (unsigned short)u;
}
__device__ inline float bf2f(unsigned short h){
    return __uint_as_float(((unsigned int)h)<<16);
}
__device__ inline unsigned int cvt_pk(float a, float b){
    unsigned int r;
    asm volatile("v_cvt_pk_bf16_f32 %0, %1, %2" : "=v"(r) : "v"(a), "v"(b));
    return r;
}
__device__ inline void split8(const float* f, bf16x8_t& h, bf16x8_t& l){
    U4 uh, ul;
    #pragma unroll
    for (int j = 0; j < 8; j++){
        unsigned short hv = f2bf(f[j]);
        uh.s[j] = hv;
        ul.s[j] = f2bf(f[j] - bf2f(hv));
    }
    h = uh.v; l = ul.v;
}

// ---------------------------------------------------------------------------
// GEMM 1: qkv = x @ qkv_w^T + qkv_b, scattered into q,k,v [B,H,N,HD]  (fp32)
// (unchanged from round 1 — proven)
// ---------------------------------------------------------------------------
__global__ __launch_bounds__(256) void gemm_qkv(const float* __restrict__ X,
        const float* __restrict__ W, const float* __restrict__ bias,
        float* __restrict__ q, float* __restrict__ k, float* __restrict__ v)
{
    __shared__ float as[64][17];
    __shared__ float bs[64][17];
    int tid = threadIdx.x;
    int tx = tid & 15, ty = tid >> 4;
    int row0 = blockIdx.x * 64, col0 = blockIdx.y * 64;

    int lr = tid >> 2;
    int lk = (tid & 3) * 4;
    int am = row0 + lr;
    bool aval = am < M_ROWS;
    int ab = aval ? am / NTOK : 0, an = aval ? am % NTOK : 0;
    const float* asrc = X + ((size_t)an * NB + ab) * NC;
    const float* bsrc = W + (size_t)(col0 + lr) * NC;

    float acc[4][4];
    #pragma unroll
    for (int i = 0; i < 4; i++)
        #pragma unroll
        for (int j = 0; j < 4; j++) acc[i][j] = 0.f;

    for (int k0 = 0; k0 < NC; k0 += 16) {
        if (aval) {
            float4 t = *(const float4*)(asrc + k0 + lk);
            as[lr][lk+0]=t.x; as[lr][lk+1]=t.y; as[lr][lk+2]=t.z; as[lr][lk+3]=t.w;
        } else {
            as[lr][lk+0]=0.f; as[lr][lk+1]=0.f; as[lr][lk+2]=0.f; as[lr][lk+3]=0.f;
        }
        {
            float4 t = *(const float4*)(bsrc + k0 + lk);
            bs[lr][lk+0]=t.x; bs[lr][lk+1]=t.y; bs[lr][lk+2]=t.z; bs[lr][lk+3]=t.w;
        }
        __syncthreads();
        #pragma unroll
        for (int kk = 0; kk < 16; kk++) {
            float af[4], bf[4];
            #pragma unroll
            for (int i = 0; i < 4; i++) af[i] = as[ty*4+i][kk];
            #pragma unroll
            for (int j = 0; j < 4; j++) bf[j] = bs[tx*4+j][kk];
            #pragma unroll
            for (int i = 0; i < 4; i++)
                #pragma unroll
                for (int j = 0; j < 4; j++) acc[i][j] += af[i]*bf[j];
        }
        __syncthreads();
    }
    #pragma unroll
    for (int i = 0; i < 4; i++) {
        int m = row0 + ty*4 + i;
        if (m >= M_ROWS) continue;
        int b_ = m / NTOK, n_ = m % NTOK;
        #pragma unroll
        for (int j = 0; j < 4; j++) {
            int col = col0 + tx*4 + j;
            float val = acc[i][j] + bias[col];
            int t = col >> 10, h = (col >> 6) & 15, d = col & 63;
            float* dst = (t == 0) ? q : (t == 1 ? k : v);
            dst[(((size_t)b_*NH + h)*NTOK + n_)*HD + d] = val;
        }
    }
}

// ---------------------------------------------------------------------------
// GEMM 2: out[n,b,:] = alpha*(heads[b,:,n,:] @ proj_w^T) + proj_b  (fp32)
// (unchanged from round 1 — proven)
// ---------------------------------------------------------------------------
__global__ __launch_bounds__(256) void gemm_proj(const float* __restrict__ Hd,
        const float* __restrict__ W, const float* __restrict__ bias,
        float* __restrict__ out, float alpha)
{
    __shared__ float as[64][17];
    __shared__ float bs[64][17];
    int tid = threadIdx.x;
    int tx = tid & 15, ty = tid >> 4;
    int row0 = blockIdx.x * 64, col0 = blockIdx.y * 64;

    int lr = tid >> 2;
    int lk = (tid & 3) * 4;
    int am = row0 + lr;
    bool aval = am < M_ROWS;
    int ab = aval ? am / NTOK : 0, an = aval ? am % NTOK : 0;
    const float* bsrc = W + (size_t)(col0 + lr) * NC;

    float acc[4][4];
    #pragma unroll
    for (int i = 0; i < 4; i++)
        #pragma unroll
        for (int j = 0; j < 4; j++) acc[i][j] = 0.f;

    for (int k0 = 0; k0 < NC; k0 += 16) {
        int c = k0 + lk;
        int h = c >> 6, d = c & 63;
        if (aval) {
            float4 t = *(const float4*)(Hd + (((size_t)ab*NH + h)*NTOK + an)*HD + d);
            as[lr][lk+0]=t.x; as[lr][lk+1]=t.y; as[lr][lk+2]=t.z; as[lr][lk+3]=t.w;
        } else {
            as[lr][lk+0]=0.f; as[lr][lk+1]=0.f; as[lr][lk+2]=0.f; as[lr][lk+3]=0.f;
        }
        {
            float4 t = *(const float4*)(bsrc + k0 + lk);
            bs[lr][lk+0]=t.x; bs[lr][lk+1]=t.y; bs[lr][lk+2]=t.z; bs[lr][lk+3]=t.w;
        }
        __syncthreads();
        #pragma unroll
        for (int kk = 0; kk < 16; kk++) {
            float af[4], bf[4];
            #pragma unroll
            for (int i = 0; i < 4; i++) af[i] = as[ty*4+i][kk];
            #pragma unroll
            for (int j = 0; j < 4; j++) bf[j] = bs[tx*4+j][kk];
            #pragma unroll
            for (int i = 0; i < 4; i++)
                #pragma unroll
                for (int j = 0; j < 4; j++) acc[i][j] += af[i]*bf[j];
        }
        __syncthreads();
    }
    #pragma unroll
    for (int i = 0; i < 4; i++) {
        int m = row0 + ty*4 + i;
        if (m >= M_ROWS) continue;
        int b_ = m / NTOK, n_ = m % NTOK;
        #pragma unroll
        for (int j = 0; j < 4; j++) {
            int col = col0 + tx*4 + j;
            out[((size_t)n_*NB + b_)*NC + col] = alpha * acc[i][j] + bias[col];
        }
    }
}

// ---------------------------------------------------------------------------
// MFMA flash attention, fp32 in/out. Scores via on-the-fly bf16x3 split
// (err ~2^-16); P bf16; V hi-bf16. All row indices CLAMPED -> zero OOB reads.
// Q,K,V,O: fp32 [B,H,577,64]. One wave = 32 q-rows of one (b,h).
// 640 blocks x 256 threads (4 waves), no LDS.
// FIX vs round 4: per-tile O-rescale must use the corr of the row the
// accumulator element belongs to (crow), not the lane's softmax row (lq).
// ---------------------------------------------------------------------------
__global__ __launch_bounds__(256) void flash_mfma(
    const float* __restrict__ Qf, const float* __restrict__ Kf,
    const float* __restrict__ Vf, float* __restrict__ Of,
    const float* __restrict__ itemp, float cscale, int acc)
{
    int w    = threadIdx.x >> 6;
    int lane = threadIdx.x & 63;
    int bid  = blockIdx.x;
    int bh   = (bid & 7) * 16 + (bid >> 3) / 5;    // b = bid&7 (XCD-friendly)
    int qt   = ((bid >> 3) % 5) * 4 + w;
    if (qt >= 19) return;
    int hi = lane >> 5, lq = lane & 31;
    float scale = itemp ? itemp[bh >> 4] : cscale;
    const size_t base = (size_t)bh * NTOK * HD;

    // Q fragments (B-operand): row = qt*32+lq (clamped), k-chunk c: d=16c+8hi+j
    int qrow = qt*32 + lq;
    int qr = qrow < NTOK ? qrow : NTOK-1;          // clamp: dup of row 576
    const float* qsrc = Qf + base + (size_t)qr*HD + 8*hi;
    bf16x8_t qh[4], ql[4];
    #pragma unroll
    for (int c = 0; c < 4; c++){
        float f[8];
        float4 t0 = *(const float4*)(qsrc + 16*c);
        float4 t1 = *(const float4*)(qsrc + 16*c + 4);
        f[0]=t0.x; f[1]=t0.y; f[2]=t0.z; f[3]=t0.w;
        f[4]=t1.x; f[5]=t1.y; f[6]=t1.z; f[7]=t1.w;
        split8(f, qh[c], ql[c]);
    }

    f32x16_t od0, od1;
    #pragma unroll
    for (int r = 0; r < 16; r++){ od0[r]=0.f; od1[r]=0.f; }
    float m_ = -1e30f, l_ = 0.f;

    for (int kt = 0; kt < 19; kt++){
        int krow = kt*32 + lq;
        int kr = krow < NTOK ? krow : NTOK-1;      // clamp (masked below)
        const float* ksrc = Kf + base + (size_t)kr*HD + 8*hi;
        bf16x8_t kh[4], kl[4];
        #pragma unroll
        for (int c = 0; c < 4; c++){
            float f[8];
            float4 t0 = *(const float4*)(ksrc + 16*c);
            float4 t1 = *(const float4*)(ksrc + 16*c + 4);
            f[0]=t0.x; f[1]=t0.y; f[2]=t0.z; f[3]=t0.w;
            f[4]=t1.x; f[5]=t1.y; f[6]=t1.z; f[7]=t1.w;
            split8(f, kh[c], kl[c]);
        }
        // S^T[key][q] = sum_d K[key][d]Q[q][d], bf16x3
        f32x16_t sf;
        #pragma unroll
        for (int r = 0; r < 16; r++) sf[r] = 0.f;
        #pragma unroll
        for (int c = 0; c < 4; c++){
            sf = __builtin_amdgcn_mfma_f32_32x32x16_bf16(kh[c], qh[c], sf, 0,0,0);
            sf = __builtin_amdgcn_mfma_f32_32x32x16_bf16(kh[c], ql[c], sf, 0,0,0);
            sf = __builtin_amdgcn_mfma_f32_32x32x16_bf16(kl[c], qh[c], sf, 0,0,0);
        }
        // online softmax; lane owns q-row lq; key(r) = kt*32 + (r&3)+8*(r>>2)+4*hi
        float p[16];
        float tm = -1e30f;
        if (kt == 18){
            #pragma unroll
            for (int r = 0; r < 16; r++){
                int key = 576 + (r&3) + 8*(r>>2) + 4*hi;
                p[r] = (key < NTOK) ? sf[r]*scale : -1e30f;
                tm = fmaxf(tm, p[r]);
            }
        } else {
            #pragma unroll
            for (int r = 0; r < 16; r++){ p[r] = sf[r]*scale; tm = fmaxf(tm, p[r]); }
        }
        tm = fmaxf(tm, __shfl_xor(tm, 32));
        float mn = fmaxf(m_, tm);
        float corr = __expf(m_ - mn);
        float ps = 0.f;
        #pragma unroll
        for (int r = 0; r < 16; r++){ p[r] = __expf(p[r] - mn); ps += p[r]; }
        ps += __shfl_xor(ps, 32);
        l_ = l_*corr + ps;
        m_ = mn;
        // rescale accumulator: od[r] belongs to q-row crow, use THAT row's corr
        #pragma unroll
        for (int r = 0; r < 16; r++){
            int crow = (r&3) + 8*(r>>2) + 4*hi;
            float cR = __shfl(corr, crow);
            od0[r] *= cR; od1[r] *= cR;
        }

        // P -> A-fragments (A row = q = lane&31, k = 8*hi + j within 16-key slot)
        U4 pa[2];
        #pragma unroll
        for (int ks = 0; ks < 2; ks++){
            unsigned int X0 = cvt_pk(p[8*ks+0], p[8*ks+1]);   // keys 0,1   (+8hi)
            unsigned int X1 = cvt_pk(p[8*ks+2], p[8*ks+3]);   // keys 2,3
            unsigned int X2 = cvt_pk(p[8*ks+4], p[8*ks+5]);   // keys 8,9
            unsigned int X3 = cvt_pk(p[8*ks+6], p[8*ks+7]);   // keys 10,11
            unsigned int Y0 = (unsigned int)__shfl_xor((int)X2, 32);
            unsigned int Y1 = (unsigned int)__shfl_xor((int)X3, 32);
            unsigned int Y2 = (unsigned int)__shfl_xor((int)X0, 32);
            unsigned int Y3 = (unsigned int)__shfl_xor((int)X1, 32);
            pa[ks].u[0] = hi ? Y0 : X0;
            pa[ks].u[1] = hi ? Y1 : X1;
            pa[ks].u[2] = hi ? X2 : Y2;
            pa[ks].u[3] = hi ? X3 : Y3;
        }
        // V B-fragments gathered from fp32 V (clamped + masked):
        // element j = V[key=kt*32+16ks+8hi+j][d = 32*half + lq]
        U4 vf0[2], vf1[2];
        #pragma unroll
        for (int ks = 0; ks < 2; ks++){
            int key0 = kt*32 + 16*ks + 8*hi;
            #pragma unroll
            for (int j = 0; j < 8; j++){
                int key = key0 + j;
                int kc = key < NTOK ? key : NTOK-1;
                const float* vsrc = Vf + base + (size_t)kc*HD + lq;
                float v0 = vsrc[0], v1 = vsrc[32];
                vf0[ks].s[j] = key < NTOK ? f2bf(v0) : (unsigned short)0;
                vf1[ks].s[j] = key < NTOK ? f2bf(v1) : (unsigned short)0;
            }
        }
        od0 = __builtin_amdgcn_mfma_f32_32x32x16_bf16(pa[0].v, vf0[0].v, od0, 0,0,0);
        od0 = __builtin_amdgcn_mfma_f32_32x32x16_bf16(pa[1].v, vf0[1].v, od0, 0,0,0);
        od1 = __builtin_amdgcn_mfma_f32_32x32x16_bf16(pa[0].v, vf1[0].v, od1, 0,0,0);
        od1 = __builtin_amdgcn_mfma_f32_32x32x16_bf16(pa[1].v, vf1[1].v, od1, 0,0,0);
    }

    float linv = 1.f / l_;
    #pragma unroll
    for (int r = 0; r < 16; r++){
        int crow = (r&3) + 8*(r>>2) + 4*hi;        // q-row within tile
        int qg = qt*32 + crow;
        float li = __shfl(linv, crow);             // lane crow holds row crow
        if (qg < NTOK){
            size_t o0 = base + (size_t)qg*HD + lq;
            float a0 = od0[r]*li, a1 = od1[r]*li;
            if (acc){ a0 += Of[o0]; a1 += Of[o0+32]; }
            Of[o0] = a0; Of[o0+32] = a1;
        }
    }
}

// ---------------------------------------------------------------------------
// per-(b,n) L2 norm of x rows -> rn  (unchanged, proven)
// ---------------------------------------------------------------------------
__global__ __launch_bounds__(256) void row_norm(const float* __restrict__ X,
                                                float* __restrict__ rn)
{
    int id = blockIdx.x;
    int b = id / NTOK, n = id % NTOK;
    const float* src = X + ((size_t)n*NB + b)*NC;
    int tid = threadIdx.x;
    float s = 0.f;
    for (int i = tid; i < NC; i += 256) { float t = src[i]; s += t*t; }
    #pragma unroll
    for (int o = 1; o < 64; o <<= 1) s += __shfl_xor(s, o);
    __shared__ float red[4];
    if ((tid & 63) == 0) red[tid >> 6] = s;
    __syncthreads();
    if (tid == 0) rn[id] = sqrtf(red[0] + red[1] + red[2] + red[3]);
}

__global__ __launch_bounds__(256) void calc_invtemp(const float* __restrict__ rn,
                                                    float* __restrict__ it)
{
    int b = blockIdx.x;
    int tid = threadIdx.x;
    float s = 0.f;
    for (int i = tid; i < NTOK; i += 256) s += rn[b*NTOK + i];
    #pragma unroll
    for (int o = 1; o < 64; o <<= 1) s += __shfl_xor(s, o);
    __shared__ float red[4];
    if ((tid & 63) == 0) red[tid >> 6] = s;
    __syncthreads();
    if (tid == 0) it[b] = (red[0]+red[1]+red[2]+red[3]) / (float)NTOK * 0.125f;
}

// ---------------------------------------------------------------------------
// row-wise L2 normalize, rows of 64  (unchanged, proven)
// ---------------------------------------------------------------------------
__global__ __launch_bounds__(256) void l2n_rows(const float* __restrict__ in,
                                                float* __restrict__ out)
{
    size_t row = (size_t)blockIdx.x * 4 + (threadIdx.x >> 6);
    int lane = threadIdx.x & 63;
    float x = in[row*HD + lane];
    float s = x*x;
    #pragma unroll
    for (int o = 1; o < 64; o <<= 1) s += __shfl_xor(s, o);
    float nrm = fmaxf(sqrtf(s), 1e-12f);
    out[row*HD + lane] = x / nrm;
}

// ---------------------------------------------------------------------------
extern "C" void kernel_launch(void* const* d_in, const int* in_sizes, int n_in,
                              void* d_out, int out_size, void* d_ws, size_t ws_size,
                              hipStream_t stream)
{
    const float* x      = (const float*)d_in[0];
    const float* qkv_w  = (const float*)d_in[1];
    const float* qkv_b  = (const float*)d_in[2];
    const float* proj_w = (const float*)d_in[3];
    const float* proj_b = (const float*)d_in[4];
    float* out = (float*)d_out;            // [0,SZ)=x_gem, [SZ,2SZ)=x_ori
    float* ws  = (float*)d_ws;

    float* q  = ws;
    float* k  = ws + SZ;
    float* v  = ws + 2*SZ;
    float* b4 = ws + 3*SZ;
    float* rn = ws + 4*SZ;
    float* it = rn + M_ROWS;
    float* b5 = out;                       // x_gem half doubles as scratch

    dim3 blk(256);
    dim3 gqkv(73, 48), gproj(73, 16), gfl(640);

    // q,k,v
    gemm_qkv<<<gqkv, blk, 0, stream>>>(x, qkv_w, qkv_b, q, k, v);
    // inv_temp
    row_norm<<<dim3(M_ROWS), blk, 0, stream>>>(x, rn);
    calc_invtemp<<<dim3(NB), blk, 0, stream>>>(rn, it);
    // x_ori = proj(softmax(qk/8)v)
    flash_mfma<<<gfl, blk, 0, stream>>>(q, k, v, b4, nullptr, 0.125f, 0);
    gemm_proj<<<gproj, blk, 0, stream>>>(b4, proj_w, proj_b, out + SZ, 1.f);
    // xs_i = l2n(v,k,q);   k,q normalized in place (dead otherwise)
    l2n_rows<<<dim3(18464), blk, 0, stream>>>(v, b4);   // xs1
    l2n_rows<<<dim3(18464), blk, 0, stream>>>(k, k);    // xs2
    l2n_rows<<<dim3(18464), blk, 0, stream>>>(q, q);    // xs3
    // one self-attn iteration: ys_i = softmax(xs_i xs_i^T * it) xs_i
    flash_mfma<<<gfl, blk, 0, stream>>>(b4, b4, b4, b5, it, 0.f, 0);  // ys1
    flash_mfma<<<gfl, blk, 0, stream>>>(k,  k,  k,  b4, it, 0.f, 0);  // ys2
    flash_mfma<<<gfl, blk, 0, stream>>>(q,  q,  q,  k,  it, 0.f, 0);  // ys3
    // z_i = l2n(ys_i), in place
    l2n_rows<<<dim3(18464), blk, 0, stream>>>(b5, b5);
    l2n_rows<<<dim3(18464), blk, 0, stream>>>(b4, b4);
    l2n_rows<<<dim3(18464), blk, 0, stream>>>(k,  k);
    // sum_i softmax(z_i z_i^T * it) @ v  -> q
    flash_mfma<<<gfl, blk, 0, stream>>>(b5, b5, v, q, it, 0.f, 0);
    flash_mfma<<<gfl, blk, 0, stream>>>(b4, b4, v, q, it, 0.f, 1);
    flash_mfma<<<gfl, blk, 0, stream>>>(k,  k,  v, q, it, 0.f, 1);
    // x_gem = proj(sum/3)
    gemm_proj<<<gproj, blk, 0, stream>>>(q, proj_w, proj_b, out, 1.f/3.f);
}

// Round 6
// 1159.855 us; speedup vs baseline: 4.1359x; 1.4367x over previous
//
#include <hip/hip_runtime.h>
#include <math.h>

#define NTOK 577
#define NB 8
#define NC 1024
#define NH 16
#define HD 64
#define M_ROWS (NB*NTOK)               // 4616
#define SZ ((size_t)NB*NH*NTOK*HD)     // 4726784 floats = B*N*C = 4616*1024
#define WSZ ((size_t)3*NC*NC)          // 3145728 (qkv_w rows*cols)
#define PSZ ((size_t)NC*NC)            // 1048576

typedef __attribute__((ext_vector_type(8)))  short bf16x8_t;
typedef __attribute__((ext_vector_type(16))) float f32x16_t;

union U4 { unsigned short s[8]; unsigned int u[4]; bf16x8_t v; };

__device__ inline unsigned short f2bf(float x){
    unsigned int u = __float_as_uint(x);
    u = (u + 0x7FFFu + ((u>>16)&1u)) >> 16;
    return (unsigned short)u;
}
__device__ inline float bf2f(unsigned short h){
    return __uint_as_float(((unsigned int)h)<<16);
}
__device__ inline unsigned int cvt_pk(float a, float b){
    unsigned int r;
    asm volatile("v_cvt_pk_bf16_f32 %0, %1, %2" : "=v"(r) : "v"(a), "v"(b));
    return r;
}
__device__ inline void split8(const float* f, bf16x8_t& h, bf16x8_t& l){
    U4 uh, ul;
    #pragma unroll
    for (int j = 0; j < 8; j++){
        unsigned short hv = f2bf(f[j]);
        uh.s[j] = hv;
        ul.s[j] = f2bf(f[j] - bf2f(hv));
    }
    h = uh.v; l = ul.v;
}

// ---------------------------------------------------------------------------
// split fp32 rows -> bf16 hi/lo rows [nrows][1024]
// mode 0: src row-major [nrows][1024]
// mode 1: X [N,B,C]: row m=b*577+n -> src row (n*8+b)
// mode 2: F [B,H,577,64]: row m=b*577+n, col c -> F[b][c/64][n][c%64]
// ---------------------------------------------------------------------------
__global__ __launch_bounds__(256) void split_rows(const float* __restrict__ src,
        unsigned short* __restrict__ dh, unsigned short* __restrict__ dl, int mode)
{
    int row = blockIdx.x, t = threadIdx.x;
    const float* s;
    if (mode == 0) s = src + (size_t)row*NC + 4*t;
    else {
        int b = row / NTOK, n = row % NTOK;
        if (mode == 1) s = src + ((size_t)n*NB + b)*NC + 4*t;
        else {
            int h = t >> 4, d = (4*t) & 63;
            s = src + (((size_t)b*NH + h)*NTOK + n)*HD + d;
        }
    }
    float4 v = *(const float4*)s;
    ushort4 hv, lv;
    hv.x = f2bf(v.x); lv.x = f2bf(v.x - bf2f(hv.x));
    hv.y = f2bf(v.y); lv.y = f2bf(v.y - bf2f(hv.y));
    hv.z = f2bf(v.z); lv.z = f2bf(v.z - bf2f(hv.z));
    hv.w = f2bf(v.w); lv.w = f2bf(v.w - bf2f(hv.w));
    *(ushort4*)(dh + (size_t)row*NC + 4*t) = hv;
    *(ushort4*)(dl + (size_t)row*NC + 4*t) = lv;
}

// ---------------------------------------------------------------------------
// MFMA GEMM: C[m][n] = sum_k A[m][k]*B[n][k], A/B split bf16 hi/lo (bf16x3).
// Block 256 thr = 4 waves (2x2), tile 128x128, wave 64x64, frags 2x2 of 32x32.
// mode 0: qkv epilogue (+qkv_b, scatter to q/k/v [B,H,577,64] fp32)
// mode 1: proj epilogue (out[(n*8+b)*1024+col] = alpha*val + bias[col])
// Fragment layouts identical to the HW-verified flash_mfma usage.
// ---------------------------------------------------------------------------
__global__ __launch_bounds__(256) void gemm_mfma(
    const unsigned short* __restrict__ Ah, const unsigned short* __restrict__ Al,
    const unsigned short* __restrict__ Bh, const unsigned short* __restrict__ Bl,
    const float* __restrict__ bias, float alpha,
    float* __restrict__ o0, float* __restrict__ o1, float* __restrict__ o2,
    int mode)
{
    int l = threadIdx.x & 63, w = threadIdx.x >> 6;
    int lq = l & 31, hi = l >> 5;
    int col0 = blockIdx.x*128 + (w & 1)*64;
    int row0 = blockIdx.y*128 + (w >> 1)*64;

    int ar0 = row0 + lq;      if (ar0 >= M_ROWS) ar0 = M_ROWS-1;
    int ar1 = row0 + 32 + lq; if (ar1 >= M_ROWS) ar1 = M_ROWS-1;
    const unsigned short* pa0h = Ah + (size_t)ar0*NC + 8*hi;
    const unsigned short* pa0l = Al + (size_t)ar0*NC + 8*hi;
    const unsigned short* pa1h = Ah + (size_t)ar1*NC + 8*hi;
    const unsigned short* pa1l = Al + (size_t)ar1*NC + 8*hi;
    const unsigned short* pb0h = Bh + (size_t)(col0 + lq)*NC + 8*hi;
    const unsigned short* pb0l = Bl + (size_t)(col0 + lq)*NC + 8*hi;
    const unsigned short* pb1h = Bh + (size_t)(col0 + 32 + lq)*NC + 8*hi;
    const unsigned short* pb1l = Bl + (size_t)(col0 + 32 + lq)*NC + 8*hi;

    f32x16_t acc[2][2];
    #pragma unroll
    for (int i = 0; i < 16; i++){
        acc[0][0][i]=0.f; acc[0][1][i]=0.f; acc[1][0][i]=0.f; acc[1][1][i]=0.f;
    }

    for (int k0 = 0; k0 < NC; k0 += 16){
        bf16x8_t a0h = *(const bf16x8_t*)(pa0h + k0);
        bf16x8_t a1h = *(const bf16x8_t*)(pa1h + k0);
        bf16x8_t b0h = *(const bf16x8_t*)(pb0h + k0);
        bf16x8_t b1h = *(const bf16x8_t*)(pb1h + k0);
        bf16x8_t a0l = *(const bf16x8_t*)(pa0l + k0);
        bf16x8_t a1l = *(const bf16x8_t*)(pa1l + k0);
        bf16x8_t b0l = *(const bf16x8_t*)(pb0l + k0);
        bf16x8_t b1l = *(const bf16x8_t*)(pb1l + k0);
        acc[0][0] = __builtin_amdgcn_mfma_f32_32x32x16_bf16(a0h, b0h, acc[0][0], 0,0,0);
        acc[0][1] = __builtin_amdgcn_mfma_f32_32x32x16_bf16(a0h, b1h, acc[0][1], 0,0,0);
        acc[1][0] = __builtin_amdgcn_mfma_f32_32x32x16_bf16(a1h, b0h, acc[1][0], 0,0,0);
        acc[1][1] = __builtin_amdgcn_mfma_f32_32x32x16_bf16(a1h, b1h, acc[1][1], 0,0,0);
        acc[0][0] = __builtin_amdgcn_mfma_f32_32x32x16_bf16(a0h, b0l, acc[0][0], 0,0,0);
        acc[0][1] = __builtin_amdgcn_mfma_f32_32x32x16_bf16(a0h, b1l, acc[0][1], 0,0,0);
        acc[1][0] = __builtin_amdgcn_mfma_f32_32x32x16_bf16(a1h, b0l, acc[1][0], 0,0,0);
        acc[1][1] = __builtin_amdgcn_mfma_f32_32x32x16_bf16(a1h, b1l, acc[1][1], 0,0,0);
        acc[0][0] = __builtin_amdgcn_mfma_f32_32x32x16_bf16(a0l, b0h, acc[0][0], 0,0,0);
        acc[0][1] = __builtin_amdgcn_mfma_f32_32x32x16_bf16(a0l, b1h, acc[0][1], 0,0,0);
        acc[1][0] = __builtin_amdgcn_mfma_f32_32x32x16_bf16(a1l, b0h, acc[1][0], 0,0,0);
        acc[1][1] = __builtin_amdgcn_mfma_f32_32x32x16_bf16(a1l, b1h, acc[1][1], 0,0,0);
    }

    #pragma unroll
    for (int fn = 0; fn < 2; fn++){
        int colb = col0 + fn*32 + lq;
        float bb = bias[colb];
        int tt = colb >> 10, h = (colb >> 6) & 15, d = colb & 63;
        float* dst = (mode == 0) ? (tt == 0 ? o0 : (tt == 1 ? o1 : o2)) : o0;
        #pragma unroll
        for (int fm = 0; fm < 2; fm++){
            #pragma unroll
            for (int r = 0; r < 16; r++){
                int orow = row0 + fm*32 + (r&3) + 8*(r>>2) + 4*hi;
                if (orow < M_ROWS){
                    float val = acc[fm][fn][r];
                    int b = orow / NTOK, n = orow % NTOK;
                    if (mode == 0){
                        dst[(((size_t)b*NH + h)*NTOK + n)*HD + d] = val + bb;
                    } else {
                        dst[((size_t)n*NB + b)*NC + colb] = alpha*val + bb;
                    }
                }
            }
        }
    }
}

// ---------------------------------------------------------------------------
// MFMA flash attention (unchanged from round 5 — proven)
// ---------------------------------------------------------------------------
__global__ __launch_bounds__(256) void flash_mfma(
    const float* __restrict__ Qf, const float* __restrict__ Kf,
    const float* __restrict__ Vf, float* __restrict__ Of,
    const float* __restrict__ itemp, float cscale, int acc)
{
    int w    = threadIdx.x >> 6;
    int lane = threadIdx.x & 63;
    int bid  = blockIdx.x;
    int bh   = (bid & 7) * 16 + (bid >> 3) / 5;
    int qt   = ((bid >> 3) % 5) * 4 + w;
    if (qt >= 19) return;
    int hi = lane >> 5, lq = lane & 31;
    float scale = itemp ? itemp[bh >> 4] : cscale;
    const size_t base = (size_t)bh * NTOK * HD;

    int qrow = qt*32 + lq;
    int qr = qrow < NTOK ? qrow : NTOK-1;
    const float* qsrc = Qf + base + (size_t)qr*HD + 8*hi;
    bf16x8_t qh[4], ql[4];
    #pragma unroll
    for (int c = 0; c < 4; c++){
        float f[8];
        float4 t0 = *(const float4*)(qsrc + 16*c);
        float4 t1 = *(const float4*)(qsrc + 16*c + 4);
        f[0]=t0.x; f[1]=t0.y; f[2]=t0.z; f[3]=t0.w;
        f[4]=t1.x; f[5]=t1.y; f[6]=t1.z; f[7]=t1.w;
        split8(f, qh[c], ql[c]);
    }

    f32x16_t od0, od1;
    #pragma unroll
    for (int r = 0; r < 16; r++){ od0[r]=0.f; od1[r]=0.f; }
    float m_ = -1e30f, l_ = 0.f;

    for (int kt = 0; kt < 19; kt++){
        int krow = kt*32 + lq;
        int kr = krow < NTOK ? krow : NTOK-1;
        const float* ksrc = Kf + base + (size_t)kr*HD + 8*hi;
        bf16x8_t kh[4], kl[4];
        #pragma unroll
        for (int c = 0; c < 4; c++){
            float f[8];
            float4 t0 = *(const float4*)(ksrc + 16*c);
            float4 t1 = *(const float4*)(ksrc + 16*c + 4);
            f[0]=t0.x; f[1]=t0.y; f[2]=t0.z; f[3]=t0.w;
            f[4]=t1.x; f[5]=t1.y; f[6]=t1.z; f[7]=t1.w;
            split8(f, kh[c], kl[c]);
        }
        f32x16_t sf;
        #pragma unroll
        for (int r = 0; r < 16; r++) sf[r] = 0.f;
        #pragma unroll
        for (int c = 0; c < 4; c++){
            sf = __builtin_amdgcn_mfma_f32_32x32x16_bf16(kh[c], qh[c], sf, 0,0,0);
            sf = __builtin_amdgcn_mfma_f32_32x32x16_bf16(kh[c], ql[c], sf, 0,0,0);
            sf = __builtin_amdgcn_mfma_f32_32x32x16_bf16(kl[c], qh[c], sf, 0,0,0);
        }
        float p[16];
        float tm = -1e30f;
        if (kt == 18){
            #pragma unroll
            for (int r = 0; r < 16; r++){
                int key = 576 + (r&3) + 8*(r>>2) + 4*hi;
                p[r] = (key < NTOK) ? sf[r]*scale : -1e30f;
                tm = fmaxf(tm, p[r]);
            }
        } else {
            #pragma unroll
            for (int r = 0; r < 16; r++){ p[r] = sf[r]*scale; tm = fmaxf(tm, p[r]); }
        }
        tm = fmaxf(tm, __shfl_xor(tm, 32));
        float mn = fmaxf(m_, tm);
        float corr = __expf(m_ - mn);
        float ps = 0.f;
        #pragma unroll
        for (int r = 0; r < 16; r++){ p[r] = __expf(p[r] - mn); ps += p[r]; }
        ps += __shfl_xor(ps, 32);
        l_ = l_*corr + ps;
        m_ = mn;
        #pragma unroll
        for (int r = 0; r < 16; r++){
            int crow = (r&3) + 8*(r>>2) + 4*hi;
            float cR = __shfl(corr, crow);
            od0[r] *= cR; od1[r] *= cR;
        }

        U4 pa[2];
        #pragma unroll
        for (int ks = 0; ks < 2; ks++){
            unsigned int X0 = cvt_pk(p[8*ks+0], p[8*ks+1]);
            unsigned int X1 = cvt_pk(p[8*ks+2], p[8*ks+3]);
            unsigned int X2 = cvt_pk(p[8*ks+4], p[8*ks+5]);
            unsigned int X3 = cvt_pk(p[8*ks+6], p[8*ks+7]);
            unsigned int Y0 = (unsigned int)__shfl_xor((int)X2, 32);
            unsigned int Y1 = (unsigned int)__shfl_xor((int)X3, 32);
            unsigned int Y2 = (unsigned int)__shfl_xor((int)X0, 32);
            unsigned int Y3 = (unsigned int)__shfl_xor((int)X1, 32);
            pa[ks].u[0] = hi ? Y0 : X0;
            pa[ks].u[1] = hi ? Y1 : X1;
            pa[ks].u[2] = hi ? X2 : Y2;
            pa[ks].u[3] = hi ? X3 : Y3;
        }
        U4 vf0[2], vf1[2];
        #pragma unroll
        for (int ks = 0; ks < 2; ks++){
            int key0 = kt*32 + 16*ks + 8*hi;
            #pragma unroll
            for (int j = 0; j < 8; j++){
                int key = key0 + j;
                int kc = key < NTOK ? key : NTOK-1;
                const float* vsrc = Vf + base + (size_t)kc*HD + lq;
                float v0 = vsrc[0], v1 = vsrc[32];
                vf0[ks].s[j] = key < NTOK ? f2bf(v0) : (unsigned short)0;
                vf1[ks].s[j] = key < NTOK ? f2bf(v1) : (unsigned short)0;
            }
        }
        od0 = __builtin_amdgcn_mfma_f32_32x32x16_bf16(pa[0].v, vf0[0].v, od0, 0,0,0);
        od0 = __builtin_amdgcn_mfma_f32_32x32x16_bf16(pa[1].v, vf0[1].v, od0, 0,0,0);
        od1 = __builtin_amdgcn_mfma_f32_32x32x16_bf16(pa[0].v, vf1[0].v, od1, 0,0,0);
        od1 = __builtin_amdgcn_mfma_f32_32x32x16_bf16(pa[1].v, vf1[1].v, od1, 0,0,0);
    }

    float linv = 1.f / l_;
    #pragma unroll
    for (int r = 0; r < 16; r++){
        int crow = (r&3) + 8*(r>>2) + 4*hi;
        int qg = qt*32 + crow;
        float li = __shfl(linv, crow);
        if (qg < NTOK){
            size_t o0 = base + (size_t)qg*HD + lq;
            float a0 = od0[r]*li, a1 = od1[r]*li;
            if (acc){ a0 += Of[o0]; a1 += Of[o0+32]; }
            Of[o0] = a0; Of[o0+32] = a1;
        }
    }
}

// ---------------------------------------------------------------------------
__global__ __launch_bounds__(256) void row_norm(const float* __restrict__ X,
                                                float* __restrict__ rn)
{
    int id = blockIdx.x;
    int b = id / NTOK, n = id % NTOK;
    const float* src = X + ((size_t)n*NB + b)*NC;
    int tid = threadIdx.x;
    float s = 0.f;
    for (int i = tid; i < NC; i += 256) { float t = src[i]; s += t*t; }
    #pragma unroll
    for (int o = 1; o < 64; o <<= 1) s += __shfl_xor(s, o);
    __shared__ float red[4];
    if ((tid & 63) == 0) red[tid >> 6] = s;
    __syncthreads();
    if (tid == 0) rn[id] = sqrtf(red[0] + red[1] + red[2] + red[3]);
}

__global__ __launch_bounds__(256) void calc_invtemp(const float* __restrict__ rn,
                                                    float* __restrict__ it)
{
    int b = blockIdx.x;
    int tid = threadIdx.x;
    float s = 0.f;
    for (int i = tid; i < NTOK; i += 256) s += rn[b*NTOK + i];
    #pragma unroll
    for (int o = 1; o < 64; o <<= 1) s += __shfl_xor(s, o);
    __shared__ float red[4];
    if ((tid & 63) == 0) red[tid >> 6] = s;
    __syncthreads();
    if (tid == 0) it[b] = (red[0]+red[1]+red[2]+red[3]) / (float)NTOK * 0.125f;
}

// ---------------------------------------------------------------------------
__global__ __launch_bounds__(256) void l2n_rows(const float* __restrict__ in,
                                                float* __restrict__ out)
{
    size_t row = (size_t)blockIdx.x * 4 + (threadIdx.x >> 6);
    int lane = threadIdx.x & 63;
    float x = in[row*HD + lane];
    float s = x*x;
    #pragma unroll
    for (int o = 1; o < 64; o <<= 1) s += __shfl_xor(s, o);
    float nrm = fmaxf(sqrtf(s), 1e-12f);
    out[row*HD + lane] = x / nrm;
}

// ---------------------------------------------------------------------------
extern "C" void kernel_launch(void* const* d_in, const int* in_sizes, int n_in,
                              void* d_out, int out_size, void* d_ws, size_t ws_size,
                              hipStream_t stream)
{
    const float* x      = (const float*)d_in[0];
    const float* qkv_w  = (const float*)d_in[1];
    const float* qkv_b  = (const float*)d_in[2];
    const float* proj_w = (const float*)d_in[3];
    const float* proj_b = (const float*)d_in[4];
    float* out = (float*)d_out;            // [0,SZ)=x_gem, [SZ,2SZ)=x_ori
    float* ws  = (float*)d_ws;

    float* q  = ws;
    float* k  = ws + SZ;
    float* v  = ws + 2*SZ;
    float* b4 = ws + 3*SZ;
    float* b5 = out;                       // x_gem half doubles as scratch

    // bf16 split region above the fp32 slots (lifetime-aliased):
    unsigned short* su  = (unsigned short*)(ws + 4*SZ);
    unsigned short* XAh = su;              // X split      [4616][1024]
    unsigned short* XAl = su + SZ;
    unsigned short* WQh = su + 2*SZ;       // qkv_w split  [3072][1024]
    unsigned short* WQl = su + 2*SZ + WSZ;
    unsigned short* FAh = XAh;             // attn-out split (aliases XA, XA dead)
    unsigned short* FAl = XAl;
    unsigned short* WPh = WQh;             // proj_w split  (aliases WQ, WQ dead)
    unsigned short* WPl = WQh + PSZ;
    float* rn = (float*)(su + 2*SZ + 2*WSZ);
    float* it = rn + M_ROWS;

    dim3 blk(256);
    dim3 gfl(640);

    // ---- qkv = x @ qkv_w^T + b  (bf16x3 MFMA) ----
    split_rows<<<dim3(M_ROWS), blk, 0, stream>>>(x, XAh, XAl, 1);
    split_rows<<<dim3(3*NC),  blk, 0, stream>>>(qkv_w, WQh, WQl, 0);
    gemm_mfma<<<dim3(24,37), blk, 0, stream>>>(XAh, XAl, WQh, WQl,
        qkv_b, 1.f, q, k, v, 0);
    // inv_temp
    row_norm<<<dim3(M_ROWS), blk, 0, stream>>>(x, rn);
    calc_invtemp<<<dim3(NB), blk, 0, stream>>>(rn, it);
    // x_ori = proj(softmax(qk/8)v)
    flash_mfma<<<gfl, blk, 0, stream>>>(q, k, v, b4, nullptr, 0.125f, 0);
    split_rows<<<dim3(M_ROWS), blk, 0, stream>>>(b4, FAh, FAl, 2);
    split_rows<<<dim3(NC),    blk, 0, stream>>>(proj_w, WPh, WPl, 0);
    gemm_mfma<<<dim3(8,37), blk, 0, stream>>>(FAh, FAl, WPh, WPl,
        proj_b, 1.f, out + SZ, nullptr, nullptr, 1);
    // xs_i = l2n(v,k,q)
    l2n_rows<<<dim3(18464), blk, 0, stream>>>(v, b4);   // xs1
    l2n_rows<<<dim3(18464), blk, 0, stream>>>(k, k);    // xs2
    l2n_rows<<<dim3(18464), blk, 0, stream>>>(q, q);    // xs3
    // ys_i = softmax(xs_i xs_i^T * it) xs_i
    flash_mfma<<<gfl, blk, 0, stream>>>(b4, b4, b4, b5, it, 0.f, 0);  // ys1
    flash_mfma<<<gfl, blk, 0, stream>>>(k,  k,  k,  b4, it, 0.f, 0);  // ys2
    flash_mfma<<<gfl, blk, 0, stream>>>(q,  q,  q,  k,  it, 0.f, 0);  // ys3
    // z_i = l2n(ys_i)
    l2n_rows<<<dim3(18464), blk, 0, stream>>>(b5, b5);
    l2n_rows<<<dim3(18464), blk, 0, stream>>>(b4, b4);
    l2n_rows<<<dim3(18464), blk, 0, stream>>>(k,  k);
    // sum_i softmax(z_i z_i^T * it) @ v  -> q
    flash_mfma<<<gfl, blk, 0, stream>>>(b5, b5, v, q, it, 0.f, 0);
    flash_mfma<<<gfl, blk, 0, stream>>>(b4, b4, v, q, it, 0.f, 1);
    flash_mfma<<<gfl, blk, 0, stream>>>(k,  k,  v, q, it, 0.f, 1);
    // x_gem = proj(sum/3)
    split_rows<<<dim3(M_ROWS), blk, 0, stream>>>(q, FAh, FAl, 2);
    gemm_mfma<<<dim3(8,37), blk, 0, stream>>>(FAh, FAl, WPh, WPl,
        proj_b, 1.f/3.f, out, nullptr, nullptr, 1);
}